// Round 1
// baseline (2104.000 us; speedup 1.0000x reference)
//
#include <hip/hip_runtime.h>
#include <math.h>
#include <stdint.h>

#define H 128
#define NFACT 100000
#define NCOMP 2000
#define NEDGE 800000
#define BGRAPH 256
#define DF 1536
#define DC 27
#define LEPS 1e-5f

using bf16x8 = __attribute__((ext_vector_type(8))) __bf16;
using f32x4  = __attribute__((ext_vector_type(4))) float;
static_assert(sizeof(bf16x8) == 16, "bf16x8 must be 16B");

__device__ __forceinline__ float sigmoidf(float x) { return 1.0f / (1.0f + __expf(-x)); }

// RTNE float -> bf16 (finite inputs), manual so no libcall risk
__device__ __forceinline__ __bf16 f2bf(float x) {
    unsigned u = __float_as_uint(x);
    u += 0x7fffu + ((u >> 16) & 1u);
    unsigned short v = (unsigned short)(u >> 16);
    return __builtin_bit_cast(__bf16, v);
}
__device__ __forceinline__ float bf2f(__bf16 h) {
    unsigned short v = __builtin_bit_cast(unsigned short, h);
    return __uint_as_float((unsigned)v << 16);
}
__device__ __forceinline__ void split2(float x, __bf16& h, __bf16& l) {
    h = f2bf(x);
    l = f2bf(x - bf2f(h));
}
__device__ __forceinline__ f32x4 mfma16(bf16x8 a, bf16x8 b, f32x4 c) {
    return __builtin_amdgcn_mfma_f32_16x16x32_bf16(a, b, c, 0, 0, 0);
}

__device__ __forceinline__ int lowerb(const int* __restrict__ a, int n, int v) {
    int lo = 0, hi = n;
    while (lo < hi) { int mid = (lo + hi) >> 1; if (a[mid] < v) lo = mid + 1; else hi = mid; }
    return lo;
}

// ---------------- runtime detection of primary_mask storage (u8 bool vs i32) --------
__global__ void mask_detect(const unsigned char* __restrict__ m, int n, int* __restrict__ flag) {
    __shared__ int f;
    if (threadIdx.x == 0) f = 0;
    __syncthreads();
    int local = 0;
    for (int i = threadIdx.x; i < n; i += blockDim.x)
        if ((i & 3) && m[i]) local = 1;
    if (local) atomicOr(&f, 1);
    __syncthreads();
    if (threadIdx.x == 0) *flag = f;
}

// ---------------- CSR build: histogram -> exclusive scan -> permute edges ------------
__global__ __launch_bounds__(256)
void edge_hist(const int* __restrict__ dst, int* __restrict__ cnt) {
    int e = blockIdx.x * 256 + threadIdx.x;
    if (e < NEDGE) atomicAdd(&cnt[dst[e]], 1);
}

__global__ __launch_bounds__(1024)
void scan_excl(const int* __restrict__ cnt, int* __restrict__ off, int n) {
    __shared__ int part[1024];
    int t = threadIdx.x;
    int chunk = (n + 1023) >> 10;
    int lo = t * chunk, hi = lo + chunk; if (hi > n) hi = n; if (lo > n) lo = n;
    int s = 0;
    for (int i = lo; i < hi; ++i) s += cnt[i];
    part[t] = s;
    __syncthreads();
    for (int o = 1; o < 1024; o <<= 1) {
        int v = (t >= o) ? part[t - o] : 0;
        __syncthreads();
        part[t] += v;
        __syncthreads();
    }
    int run = (t == 0) ? 0 : part[t - 1];
    for (int i = lo; i < hi; ++i) { off[i] = run; run += cnt[i]; }
    if (t == 1023) off[n] = part[1023];
}

__global__ __launch_bounds__(256)
void edge_scatter(const int* __restrict__ src, const int* __restrict__ dst,
                  const float* __restrict__ ea,
                  const float* __restrict__ wmix, const float* __restrict__ bmix,
                  int* __restrict__ cur, int* __restrict__ ssrc, float* __restrict__ swt) {
    int e = blockIdx.x * 256 + threadIdx.x;
    if (e >= NEDGE) return;
    int d = dst[e];
    int pos = atomicAdd(&cur[d], 1);
    ssrc[pos] = src[e];
    swt[pos] = sigmoidf(ea[e] * wmix[0] + bmix[0]);
}

// ---------------- gather: company side (2000 rows, deg~400) -------------------------
__global__ __launch_bounds__(256)
void gather_comp(const int* __restrict__ off, const int* __restrict__ ssrc,
                 const float* __restrict__ swt, const float* __restrict__ feat,
                 float* __restrict__ out) {
    __shared__ float tmp[128];
    int d = blockIdx.x;
    int lo = off[d], hi = off[d + 1];
    int h = threadIdx.x & 127;
    int slot = threadIdx.x >> 7;
    float acc0 = 0.f, acc1 = 0.f;
    int j = lo + slot;
    for (; j + 2 < hi; j += 4) {
        int s0 = ssrc[j], s1 = ssrc[j + 2];
        float w0 = swt[j], w1 = swt[j + 2];
        acc0 += w0 * feat[(size_t)s0 * H + h];
        acc1 += w1 * feat[(size_t)s1 * H + h];
    }
    for (; j < hi; j += 2) acc0 += swt[j] * feat[(size_t)ssrc[j] * H + h];
    float acc = acc0 + acc1;
    if (slot == 1) tmp[h] = acc;
    __syncthreads();
    if (slot == 0) out[(size_t)d * H + h] = acc + tmp[h];
}

// ---------------- gather: fact side (100000 rows, deg~8, src table L2-resident) ------
__global__ __launch_bounds__(256)
void gather_fact(const int* __restrict__ off, const int* __restrict__ ssrc,
                 const float* __restrict__ swt, const float* __restrict__ feat,
                 float* __restrict__ out) {
    int d = blockIdx.x * 2 + (threadIdx.x >> 7);
    if (d >= NFACT) return;
    int h = threadIdx.x & 127;
    int lo = off[d], hi = off[d + 1];
    float acc = 0.f;
    for (int j = lo; j < hi; ++j)
        acc += swt[j] * feat[(size_t)ssrc[j] * H + h];
    out[(size_t)d * H + h] = acc;
}

// ---------------- preconvert W [128][K] fp32 -> fragment-ordered bf16 hi/lo ----------
// layout elem index: (((t*8 + nsub)*2 + hl)*64 + lane)*8 + i
// holding W[nsub*16 + (lane&15)][t*32 + (lane>>4)*8 + i]
__global__ __launch_bounds__(256)
void conv_w_frag(const float* __restrict__ W, int K, __bf16* __restrict__ out) {
    int e = blockIdx.x * 256 + threadIdx.x;
    if (e >= 128 * K) return;
    int n = e / K, k = e - n * K;
    int t = k >> 5, rem = k & 31, sub = rem >> 3, i = rem & 7;
    int nsub = n >> 4, ln = (sub << 4) | (n & 15);
    float x = W[e];
    __bf16 h, l; split2(x, h, l);
    size_t base = (((size_t)(t * 8 + nsub) * 2) * 64 + ln) * 8 + i;
    out[base] = h;
    out[base + 512] = l;      // hl stride = 64*8
}

// same, for concat [Wrel | Wroot] along K (K = 256)
__global__ __launch_bounds__(256)
void conv_w_cat(const float* __restrict__ Wrel, const float* __restrict__ Wroot,
                __bf16* __restrict__ out) {
    int e = blockIdx.x * 256 + threadIdx.x;
    if (e >= 128 * 256) return;
    int n = e >> 8, k = e & 255;
    float x = (k < 128) ? Wrel[n * 128 + k] : Wroot[n * 128 + (k - 128)];
    int t = k >> 5, rem = k & 31, sub = rem >> 3, i = rem & 7;
    int nsub = n >> 4, ln = (sub << 4) | (n & 15);
    __bf16 h, l; split2(x, h, l);
    size_t base = (((size_t)(t * 8 + nsub) * 2) * 64 + ln) * 8 + i;
    out[base] = h;
    out[base + 512] = l;
}

// ---------------- MFMA encoder GEMM, bf16x3 split, fused bias+ReLU+LayerNorm ---------
// out = LN(relu(X @ W^T + bias)) ; X [M,K] fp32 streamed + converted in-tile,
// W preconverted frag bf16 hi/lo. Block: 64 rows x 128 cols, 4 waves (col strips).
__global__ __launch_bounds__(256)
void gemm_enc_mfma(const float* __restrict__ X, const __bf16* __restrict__ Wf,
                   const float* __restrict__ bias, const float* __restrict__ gamma,
                   const float* __restrict__ beta, float* __restrict__ out,
                   int M, int K) {
    __shared__ __bf16 Ahi[64][40];   // +8 pad -> conflict-free ds_read_b128
    __shared__ __bf16 Alo[64][40];
    __shared__ float red[64][8];     // [row][{s0..s3,q0..q3} per wave]

    const int tid = threadIdx.x;
    const int lane = tid & 63;
    const int w = tid >> 6;          // wave = 32-col strip
    const int m0 = blockIdx.x * 64;
    const int fr = lane & 15;
    const int fq = lane >> 4;

    const int srow = tid >> 2;           // staging row 0..63
    const int scol = (tid & 3) * 8;      // staging col 0/8/16/24
    int arow = m0 + srow; if (arow >= M) arow = M - 1;
    const float* __restrict__ xrow = X + (size_t)arow * K + scol;

    f32x4 acc[4][2];
#pragma unroll
    for (int mi = 0; mi < 4; ++mi)
#pragma unroll
        for (int nj = 0; nj < 2; ++nj)
#pragma unroll
            for (int e = 0; e < 4; ++e) acc[mi][nj][e] = 0.f;

    const int NT = K >> 5;
    for (int t = 0; t < NT; ++t) {
        float4 av0 = *(const float4*)(xrow + t * 32);
        float4 av1 = *(const float4*)(xrow + t * 32 + 4);
        bf16x8 hv, lv;
        {
            float xs[8] = {av0.x, av0.y, av0.z, av0.w, av1.x, av1.y, av1.z, av1.w};
#pragma unroll
            for (int j = 0; j < 8; ++j) { __bf16 h, l; split2(xs[j], h, l); hv[j] = h; lv[j] = l; }
        }
        __syncthreads();               // prev iter's frag reads done
        *(bf16x8*)&Ahi[srow][scol] = hv;
        *(bf16x8*)&Alo[srow][scol] = lv;
        __syncthreads();

        const __bf16* wt = Wf + (size_t)t * 8192 + (size_t)(2 * w) * 1024 + lane * 8;
        bf16x8 bh0 = *(const bf16x8*)(wt);
        bf16x8 bl0 = *(const bf16x8*)(wt + 512);
        bf16x8 bh1 = *(const bf16x8*)(wt + 1024);
        bf16x8 bl1 = *(const bf16x8*)(wt + 1536);

        bf16x8 ah[4], al[4];
#pragma unroll
        for (int mi = 0; mi < 4; ++mi) {
            ah[mi] = *(const bf16x8*)&Ahi[mi * 16 + fr][fq * 8];
            al[mi] = *(const bf16x8*)&Alo[mi * 16 + fr][fq * 8];
        }
#pragma unroll
        for (int mi = 0; mi < 4; ++mi) {
            acc[mi][0] = mfma16(ah[mi], bh0, acc[mi][0]);
            acc[mi][0] = mfma16(al[mi], bh0, acc[mi][0]);
            acc[mi][0] = mfma16(ah[mi], bl0, acc[mi][0]);
            acc[mi][1] = mfma16(ah[mi], bh1, acc[mi][1]);
            acc[mi][1] = mfma16(al[mi], bh1, acc[mi][1]);
            acc[mi][1] = mfma16(ah[mi], bl1, acc[mi][1]);
        }
    }

    // -------- fused epilogue: bias + relu + LayerNorm over the full 128-col row ------
    const int col0 = w * 32 + fr;
    const int col1 = col0 + 16;
    const float bi0 = bias[col0], bi1 = bias[col1];
    const float g0 = gamma[col0], g1 = gamma[col1];
    const float be0 = beta[col0], be1 = beta[col1];

    float s[4][4], q[4][4];
#pragma unroll
    for (int mi = 0; mi < 4; ++mi)
#pragma unroll
        for (int r = 0; r < 4; ++r) {
            float x0 = fmaxf(acc[mi][0][r] + bi0, 0.f);
            float x1 = fmaxf(acc[mi][1][r] + bi1, 0.f);
            acc[mi][0][r] = x0; acc[mi][1][r] = x1;
            s[mi][r] = x0 + x1; q[mi][r] = x0 * x0 + x1 * x1;
        }
#pragma unroll
    for (int o = 1; o < 16; o <<= 1)
#pragma unroll
        for (int mi = 0; mi < 4; ++mi)
#pragma unroll
            for (int r = 0; r < 4; ++r) {
                s[mi][r] += __shfl_xor(s[mi][r], o);
                q[mi][r] += __shfl_xor(q[mi][r], o);
            }
    if (fr == 0) {
#pragma unroll
        for (int mi = 0; mi < 4; ++mi)
#pragma unroll
            for (int r = 0; r < 4; ++r) {
                int row = mi * 16 + fq * 4 + r;
                red[row][w] = s[mi][r];
                red[row][4 + w] = q[mi][r];
            }
    }
    __syncthreads();
#pragma unroll
    for (int mi = 0; mi < 4; ++mi)
#pragma unroll
        for (int r = 0; r < 4; ++r) {
            int rr = mi * 16 + fq * 4 + r;
            int grow = m0 + rr;
            if (grow < M) {
                float S = red[rr][0] + red[rr][1] + red[rr][2] + red[rr][3];
                float Q = red[rr][4] + red[rr][5] + red[rr][6] + red[rr][7];
                float mu = S * (1.f / 128.f);
                float var = Q * (1.f / 128.f) - mu * mu;
                float rs = rsqrtf(var + LEPS);
                out[(size_t)grow * H + col0] = (acc[mi][0][r] - mu) * rs * g0 + be0;
                out[(size_t)grow * H + col1] = (acc[mi][1][r] - mu) * rs * g1 + be1;
            }
        }
}

// ---------------- MFMA combine GEMM (fact side): K=256 concat [msg|root] -------------
// msg = LN(relu(msg@Wrel^T + brel + root@Wroot^T)), in-place on msg.
__global__ __launch_bounds__(256)
void gemm_comb_mfma(float* __restrict__ msg, const float* __restrict__ root,
                    const __bf16* __restrict__ Wf, const float* __restrict__ bias,
                    const float* __restrict__ gamma, const float* __restrict__ beta,
                    int M) {
    __shared__ __bf16 Ahi[64][40];
    __shared__ __bf16 Alo[64][40];
    __shared__ float red[64][8];

    const int tid = threadIdx.x;
    const int lane = tid & 63;
    const int w = tid >> 6;
    const int m0 = blockIdx.x * 64;
    const int fr = lane & 15;
    const int fq = lane >> 4;

    const int srow = tid >> 2;
    const int scol = (tid & 3) * 8;
    int arow = m0 + srow; if (arow >= M) arow = M - 1;
    const float* __restrict__ mrow = msg + (size_t)arow * H + scol;
    const float* __restrict__ rrow = root + (size_t)arow * H + scol;

    f32x4 acc[4][2];
#pragma unroll
    for (int mi = 0; mi < 4; ++mi)
#pragma unroll
        for (int nj = 0; nj < 2; ++nj)
#pragma unroll
            for (int e = 0; e < 4; ++e) acc[mi][nj][e] = 0.f;

#pragma unroll
    for (int t = 0; t < 8; ++t) {
        const float* srcp = (t < 4) ? (mrow + (t & 3) * 32) : (rrow + (t & 3) * 32);
        float4 av0 = *(const float4*)(srcp);
        float4 av1 = *(const float4*)(srcp + 4);
        bf16x8 hv, lv;
        {
            float xs[8] = {av0.x, av0.y, av0.z, av0.w, av1.x, av1.y, av1.z, av1.w};
#pragma unroll
            for (int j = 0; j < 8; ++j) { __bf16 h, l; split2(xs[j], h, l); hv[j] = h; lv[j] = l; }
        }
        __syncthreads();
        *(bf16x8*)&Ahi[srow][scol] = hv;
        *(bf16x8*)&Alo[srow][scol] = lv;
        __syncthreads();

        const __bf16* wt = Wf + (size_t)t * 8192 + (size_t)(2 * w) * 1024 + lane * 8;
        bf16x8 bh0 = *(const bf16x8*)(wt);
        bf16x8 bl0 = *(const bf16x8*)(wt + 512);
        bf16x8 bh1 = *(const bf16x8*)(wt + 1024);
        bf16x8 bl1 = *(const bf16x8*)(wt + 1536);

        bf16x8 ah[4], al[4];
#pragma unroll
        for (int mi = 0; mi < 4; ++mi) {
            ah[mi] = *(const bf16x8*)&Ahi[mi * 16 + fr][fq * 8];
            al[mi] = *(const bf16x8*)&Alo[mi * 16 + fr][fq * 8];
        }
#pragma unroll
        for (int mi = 0; mi < 4; ++mi) {
            acc[mi][0] = mfma16(ah[mi], bh0, acc[mi][0]);
            acc[mi][0] = mfma16(al[mi], bh0, acc[mi][0]);
            acc[mi][0] = mfma16(ah[mi], bl0, acc[mi][0]);
            acc[mi][1] = mfma16(ah[mi], bh1, acc[mi][1]);
            acc[mi][1] = mfma16(al[mi], bh1, acc[mi][1]);
            acc[mi][1] = mfma16(ah[mi], bl1, acc[mi][1]);
        }
    }

    const int col0 = w * 32 + fr;
    const int col1 = col0 + 16;
    const float bi0 = bias[col0], bi1 = bias[col1];
    const float g0 = gamma[col0], g1 = gamma[col1];
    const float be0 = beta[col0], be1 = beta[col1];

    float s[4][4], q[4][4];
#pragma unroll
    for (int mi = 0; mi < 4; ++mi)
#pragma unroll
        for (int r = 0; r < 4; ++r) {
            float x0 = fmaxf(acc[mi][0][r] + bi0, 0.f);
            float x1 = fmaxf(acc[mi][1][r] + bi1, 0.f);
            acc[mi][0][r] = x0; acc[mi][1][r] = x1;
            s[mi][r] = x0 + x1; q[mi][r] = x0 * x0 + x1 * x1;
        }
#pragma unroll
    for (int o = 1; o < 16; o <<= 1)
#pragma unroll
        for (int mi = 0; mi < 4; ++mi)
#pragma unroll
            for (int r = 0; r < 4; ++r) {
                s[mi][r] += __shfl_xor(s[mi][r], o);
                q[mi][r] += __shfl_xor(q[mi][r], o);
            }
    if (fr == 0) {
#pragma unroll
        for (int mi = 0; mi < 4; ++mi)
#pragma unroll
            for (int r = 0; r < 4; ++r) {
                int row = mi * 16 + fq * 4 + r;
                red[row][w] = s[mi][r];
                red[row][4 + w] = q[mi][r];
            }
    }
    __syncthreads();
#pragma unroll
    for (int mi = 0; mi < 4; ++mi)
#pragma unroll
        for (int r = 0; r < 4; ++r) {
            int rr = mi * 16 + fq * 4 + r;
            int grow = m0 + rr;
            if (grow < M) {
                float S = red[rr][0] + red[rr][1] + red[rr][2] + red[rr][3];
                float Q = red[rr][4] + red[rr][5] + red[rr][6] + red[rr][7];
                float mu = S * (1.f / 128.f);
                float var = Q * (1.f / 128.f) - mu * mu;
                float rs = rsqrtf(var + LEPS);
                msg[(size_t)grow * H + col0] = (acc[mi][0][r] - mu) * rs * g0 + be0;
                msg[(size_t)grow * H + col1] = (acc[mi][1][r] - mu) * rs * g1 + be1;
            }
        }
}

// ---------------- company encoder (tiny K=27) ----------------------------------------
__global__ __launch_bounds__(128)
void enc_comp(const float* __restrict__ X, const float* __restrict__ W,
              const float* __restrict__ bias, float* __restrict__ out) {
    __shared__ float xr[DC];
    int n = blockIdx.x, h = threadIdx.x;
    if (h < DC) xr[h] = X[(size_t)n * DC + h];
    __syncthreads();
    float acc = bias[h];
    const float* w = W + (size_t)h * DC;
#pragma unroll
    for (int d = 0; d < DC; ++d) acc += xr[d] * w[d];
    out[(size_t)n * H + h] = acc;
}

// ---------------- company combine -----------------------------------------------------
__global__ __launch_bounds__(128)
void combine_c(const float* __restrict__ msgc, const float* __restrict__ hc,
               const float* __restrict__ Wrel, const float* __restrict__ Wroot,
               const float* __restrict__ brel, float* __restrict__ out) {
    __shared__ float rowA[H];
    __shared__ float rowB[H];
    int n = blockIdx.x, h = threadIdx.x;
    rowA[h] = msgc[(size_t)n * H + h];
    rowB[h] = hc[(size_t)n * H + h];
    __syncthreads();
    float acc = brel[h];
    const float* wr = Wrel + (size_t)h * H;
    const float* wo = Wroot + (size_t)h * H;
#pragma unroll 4
    for (int k = 0; k < H; ++k) acc += rowA[k] * wr[k] + rowB[k] * wo[k];
    out[(size_t)n * H + h] = acc;
}

// ---------------- relu + LayerNorm over H, in place (wave per row) -------------------
__global__ __launch_bounds__(256)
void relu_ln_rows(float* __restrict__ data, int M,
                  const float* __restrict__ g, const float* __restrict__ b) {
    int row = blockIdx.x * 4 + (threadIdx.x >> 6);
    int lane = threadIdx.x & 63;
    if (row >= M) return;
    float* p = data + (size_t)row * H;
    float2 v = *(float2*)(p + lane * 2);
    float x0 = fmaxf(v.x, 0.f), x1 = fmaxf(v.y, 0.f);
    float s = x0 + x1, q = x0 * x0 + x1 * x1;
#pragma unroll
    for (int o = 32; o > 0; o >>= 1) { s += __shfl_xor(s, o); q += __shfl_xor(q, o); }
    float mu = s * (1.f / H);
    float var = q * (1.f / H) - mu * mu;
    float rs = rsqrtf(var + LEPS);
    float2 gg = *(const float2*)(g + lane * 2);
    float2 bb = *(const float2*)(b + lane * 2);
    float2 o2;
    o2.x = (x0 - mu) * rs * gg.x + bb.x;
    o2.y = (x1 - mu) * rs * gg.y + bb.y;
    *(float2*)(p + lane * 2) = o2;
}

// ---------------- pooling ------------------------------------------------------------
__global__ __launch_bounds__(128)
void pool_fact(const float* __restrict__ hf, const int* __restrict__ batch,
               float* __restrict__ pool) {
    int b = blockIdx.x, h = threadIdx.x;
    int lo = lowerb(batch, NFACT, b), hi = lowerb(batch, NFACT, b + 1);
    float acc = 0.f;
    for (int r = lo; r < hi; ++r) acc += hf[(size_t)r * H + h];
    float cnt = (float)(hi - lo); if (cnt < 1.f) cnt = 1.f;
    pool[(size_t)b * H + h] = acc / cnt;
}

// NOTE: reference applies maximum(cnt_m,1) BEFORE the where test -> fallback is dead.
__global__ __launch_bounds__(128)
void pool_comp(const float* __restrict__ hc, const int* __restrict__ batch,
               const void* __restrict__ maskp, const int* __restrict__ flag,
               float* __restrict__ pool) {
    int b = blockIdx.x, h = threadIdx.x;
    int lo = lowerb(batch, NCOMP, b), hi = lowerb(batch, NCOMP, b + 1);
    int isU8 = *flag;
    const unsigned char* m8 = (const unsigned char*)maskp;
    const int* m32 = (const int*)maskp;
    float acc = 0.f, cnt = 0.f;
    for (int r = lo; r < hi; ++r) {
        float m = isU8 ? (m8[r] ? 1.f : 0.f) : (m32[r] ? 1.f : 0.f);
        acc += m * hc[(size_t)r * H + h];
        cnt += m;
    }
    if (cnt < 1.f) cnt = 1.f;
    pool[(size_t)b * H + h] = acc / cnt;
}

// ---------------- gated readout + classifier -----------------------------------------
__global__ __launch_bounds__(128)
void gate_cls(const float* __restrict__ fp, const float* __restrict__ cp,
              const float* __restrict__ Wg, const float* __restrict__ bg,
              const float* __restrict__ Wc, const float* __restrict__ bc,
              float* __restrict__ out) {
    __shared__ float red[2];
    __shared__ float red2[2];
    int b = blockIdx.x, t = threadIdx.x;
    float f = fp[(size_t)b * H + t], c = cp[(size_t)b * H + t];
    float s = Wg[t] * f + Wg[H + t] * c;
#pragma unroll
    for (int o = 32; o > 0; o >>= 1) s += __shfl_xor(s, o);
    if ((t & 63) == 0) red[t >> 6] = s;
    __syncthreads();
    float S = red[0] + red[1];
    float alpha = sigmoidf(S + bg[0]);
    float v = (alpha * f + (1.f - alpha) * c) * Wc[t];
#pragma unroll
    for (int o = 32; o > 0; o >>= 1) v += __shfl_xor(v, o);
    if ((t & 63) == 0) red2[t >> 6] = v;
    __syncthreads();
    if (t == 0) out[b] = red2[0] + red2[1] + bc[0];
}

extern "C" void kernel_launch(void* const* d_in, const int* in_sizes, int n_in,
                              void* d_out, int out_size, void* d_ws, size_t ws_size,
                              hipStream_t stream) {
    const float* x_fact   = (const float*)d_in[0];
    const float* x_comp   = (const float*)d_in[1];
    const float* ea_fc    = (const float*)d_in[2];
    const float* ea_cf    = (const float*)d_in[3];
    const int*   src_fc   = (const int*)d_in[4];
    const int*   dst_fc   = (const int*)d_in[5];
    const int*   src_cf   = (const int*)d_in[6];
    const int*   dst_cf   = (const int*)d_in[7];
    const int*   fact_batch = (const int*)d_in[8];
    const int*   comp_batch = (const int*)d_in[9];
    const void*  pmask    = d_in[10];
    const float* W_in_f   = (const float*)d_in[11];
    const float* b_in_f   = (const float*)d_in[12];
    const float* g_in_f   = (const float*)d_in[13];
    const float* be_in_f  = (const float*)d_in[14];
    const float* W_in_c   = (const float*)d_in[15];
    const float* b_in_c   = (const float*)d_in[16];
    const float* g_in_c   = (const float*)d_in[17];
    const float* be_in_c  = (const float*)d_in[18];
    const float* w_mix    = (const float*)d_in[19];
    const float* b_mix    = (const float*)d_in[20];
    const float* Wrel_fc  = (const float*)d_in[21];
    const float* brel_fc  = (const float*)d_in[22];
    const float* Wroot_fc = (const float*)d_in[23];
    const float* Wrel_cf  = (const float*)d_in[24];
    const float* brel_cf  = (const float*)d_in[25];
    const float* Wroot_cf = (const float*)d_in[26];
    const float* g_post_f = (const float*)d_in[27];
    const float* b_post_f = (const float*)d_in[28];
    const float* g_post_c = (const float*)d_in[29];
    const float* b_post_c = (const float*)d_in[30];
    const float* W_gate   = (const float*)d_in[31];
    const float* b_gate   = (const float*)d_in[32];
    const float* W_cls    = (const float*)d_in[33];
    const float* b_cls    = (const float*)d_in[34];
    float* outp = (float*)d_out;
    (void)in_sizes; (void)n_in; (void)out_size; (void)ws_size;

    float* buf0  = (float*)d_ws;                        // hf ping  [NFACT,H]
    float* buf1  = buf0 + (size_t)NFACT * H;            // hf pong
    float* hc0   = buf1 + (size_t)NFACT * H;            // hc ping  [NCOMP,H]
    float* hc1   = hc0 + (size_t)NCOMP * H;             // hc pong
    float* msgc  = hc1 + (size_t)NCOMP * H;             // msg_c    [NCOMP,H]
    float* fpool = msgc + (size_t)NCOMP * H;            // [B,H]
    float* cpool = fpool + (size_t)BGRAPH * H;          // [B,H]
    float* swt_fc = cpool + (size_t)BGRAPH * H;         // [E]
    float* swt_cf = swt_fc + (size_t)NEDGE;             // [E]
    int*   ssrc_fc = (int*)(swt_cf + (size_t)NEDGE);    // [E]
    int*   ssrc_cf = ssrc_fc + (size_t)NEDGE;           // [E]
    int*   off_fc  = ssrc_cf + (size_t)NEDGE;           // [NCOMP+1]
    int*   cur_fc  = off_fc + (NCOMP + 1);              // [NCOMP]
    int*   off_cf  = cur_fc + NCOMP;                    // [NFACT+1]
    int*   cur_cf  = off_cf + (NFACT + 1);              // [NFACT]
    int*   flag    = cur_cf + NFACT;

    // bf16 fragment buffers (aligned to 64B), appended after int region
    uintptr_t pal = ((uintptr_t)(flag + 1) + 63) & ~(uintptr_t)63;
    __bf16* WencF = (__bf16*)pal;                       // 48*8192 = 393216 elems
    __bf16* WcfF0 = WencF + (size_t)48 * 8192;          // 8*8192 per layer
    __bf16* WcfF1 = WcfF0 + (size_t)8 * 8192;

    mask_detect<<<1, 256, 0, stream>>>((const unsigned char*)pmask, NCOMP, flag);

    // ---- weight preconversion (frag-ordered bf16 hi/lo) ----
    conv_w_frag<<<(128 * DF + 255) / 256, 256, 0, stream>>>(W_in_f, DF, WencF);
    conv_w_cat<<<(128 * 256 + 255) / 256, 256, 0, stream>>>(Wrel_cf, Wroot_cf, WcfF0);
    conv_w_cat<<<(128 * 256 + 255) / 256, 256, 0, stream>>>(Wrel_cf + (size_t)H * H,
                                                            Wroot_cf + (size_t)H * H, WcfF1);

    // ---- CSR build (once; weights reused across both layers) ----
    hipMemsetAsync(cur_fc, 0, NCOMP * sizeof(int), stream);
    hipMemsetAsync(cur_cf, 0, NFACT * sizeof(int), stream);
    edge_hist<<<(NEDGE + 255) / 256, 256, 0, stream>>>(dst_fc, cur_fc);
    edge_hist<<<(NEDGE + 255) / 256, 256, 0, stream>>>(dst_cf, cur_cf);
    scan_excl<<<1, 1024, 0, stream>>>(cur_fc, off_fc, NCOMP);
    scan_excl<<<1, 1024, 0, stream>>>(cur_cf, off_cf, NFACT);
    hipMemcpyAsync(cur_fc, off_fc, NCOMP * sizeof(int), hipMemcpyDeviceToDevice, stream);
    hipMemcpyAsync(cur_cf, off_cf, NFACT * sizeof(int), hipMemcpyDeviceToDevice, stream);
    edge_scatter<<<(NEDGE + 255) / 256, 256, 0, stream>>>(src_fc, dst_fc, ea_fc, w_mix, b_mix,
                                                          cur_fc, ssrc_fc, swt_fc);
    edge_scatter<<<(NEDGE + 255) / 256, 256, 0, stream>>>(src_cf, dst_cf, ea_cf, w_mix, b_mix,
                                                          cur_cf, ssrc_cf, swt_cf);

    // ---- encoders (fact: MFMA GEMM with fused bias+ReLU+LN) ----
    gemm_enc_mfma<<<(NFACT + 63) / 64, 256, 0, stream>>>(x_fact, WencF, b_in_f, g_in_f,
                                                         be_in_f, buf0, NFACT, DF);
    enc_comp<<<NCOMP, 128, 0, stream>>>(x_comp, W_in_c, b_in_c, hc0);
    relu_ln_rows<<<(NCOMP + 3) / 4, 256, 0, stream>>>(hc0, NCOMP, g_in_c, be_in_c);

    float* hf = buf0; float* hfN = buf1;
    float* hc = hc0;  float* hcN = hc1;

    for (int l = 0; l < 2; ++l) {
        gather_comp<<<NCOMP, 256, 0, stream>>>(off_fc, ssrc_fc, swt_fc, hf, msgc);
        gather_fact<<<(NFACT + 1) / 2, 256, 0, stream>>>(off_cf, ssrc_cf, swt_cf, hc, hfN);
        gemm_comb_mfma<<<(NFACT + 63) / 64, 256, 0, stream>>>(hfN, hf,
            (l == 0) ? WcfF0 : WcfF1, brel_cf + (size_t)l * H, g_post_f, b_post_f, NFACT);
        combine_c<<<NCOMP, 128, 0, stream>>>(msgc, hc,
            Wrel_fc + (size_t)l * H * H, Wroot_fc + (size_t)l * H * H, brel_fc + (size_t)l * H, hcN);
        relu_ln_rows<<<(NCOMP + 3) / 4, 256, 0, stream>>>(hcN, NCOMP, g_post_c, b_post_c);
        float* t = hf; hf = hfN; hfN = t;
        t = hc; hc = hcN; hcN = t;
    }

    pool_fact<<<BGRAPH, 128, 0, stream>>>(hf, fact_batch, fpool);
    pool_comp<<<BGRAPH, 128, 0, stream>>>(hc, comp_batch, pmask, flag, cpool);
    gate_cls<<<BGRAPH, 128, 0, stream>>>(fpool, cpool, W_gate, b_gate, W_cls, b_cls, outp);
}